// Round 6
// baseline (335.217 us; speedup 1.0000x reference)
//
#include <hip/hip_runtime.h>
#include <hip/hip_bf16.h>
#include <cstdint>
#include <cstddef>

#define D_MODEL 2048
#define NH 32
#define NKV 8
#define HD 64
#define BB 2
#define LL 2048
#define EPS 1e-6f
#define MM (BB * LL)   // 4096
#define QS 3072        // fused qkv row stride
#define KO 2048        // k column offset in qkv
#define VO 2560        // v column offset in qkv
// softmax fold: q pre-scaled by 0.125*log2(e); p = 2^(S - 8*log2(e))
#define QSCALE 0.18033688f
#define SM_BIAS 11.5415603f

typedef __hip_bfloat16 bf16;
typedef short bf16x8 __attribute__((ext_vector_type(8)));
typedef short s16x4 __attribute__((ext_vector_type(4)));
typedef float f32x4 __attribute__((ext_vector_type(4)));

// ---- dtype helpers ---------------------------------------------------------
__device__ inline float4 ld_bf4u(const unsigned short* p) {
  const ushort4 u = *(const ushort4*)p;
  float4 r;
  r.x = __uint_as_float(((unsigned)u.x) << 16);
  r.y = __uint_as_float(((unsigned)u.y) << 16);
  r.z = __uint_as_float(((unsigned)u.z) << 16);
  r.w = __uint_as_float(((unsigned)u.w) << 16);
  return r;
}
__device__ inline float4 ld4_rt(const void* p, size_t i, bool f32) {
  if (f32) return *(const float4*)((const float*)p + i);
  return ld_bf4u((const unsigned short*)p + i);
}
__device__ inline float ld1_rt(const void* p, size_t i, bool f32) {
  if (f32) return ((const float*)p)[i];
  unsigned short u = ((const unsigned short*)p)[i];
  return __uint_as_float(((unsigned)u) << 16);
}
__device__ inline unsigned short f2bf(float f) {
  bf16 h = __float2bfloat16(f);  // RNE
  return *reinterpret_cast<unsigned short*>(&h);
}
__device__ inline float bfu2f(unsigned short u) {
  return __uint_as_float(((unsigned)u) << 16);
}
__device__ inline void store1(float* p, float v) { *p = v; }
__device__ inline void store1(unsigned short* p, float v) { *p = f2bf(v); }

// async global->LDS, 16 B per lane; LDS dest must be wave-uniform base + lane*16
__device__ inline void glds16(const unsigned short* g, unsigned short* l) {
  __builtin_amdgcn_global_load_lds(
      (const __attribute__((address_space(1))) unsigned int*)g,
      (__attribute__((address_space(3))) unsigned int*)l, 16, 0, 0);
}

// ---- per-input dtype detector (sampled, vectorized) ------------------------
__global__ __launch_bounds__(256) void detect_all(
    const unsigned short* p0, const unsigned short* p1, const unsigned short* p2,
    const unsigned short* p3, const unsigned short* p4, const unsigned short* p5,
    const unsigned short* p6, int* __restrict__ flags) {
  const unsigned short* ptrs[7] = {p0, p1, p2, p3, p4, p5, p6};
  const int b = blockIdx.x;
  const uint4* p = (const uint4*)ptrs[b];  // 8 words per uint4
  __shared__ int found;
  if (threadIdx.x == 0) found = 0;
  __syncthreads();
  int loc = 0;
#pragma unroll
  for (int it = 0; it < 16; ++it) {
    uint4 v = p[it * 256 + threadIdx.x];
    unsigned wds[4] = {v.x, v.y, v.z, v.w};
#pragma unroll
    for (int q = 0; q < 4; ++q) {
      unsigned lo = wds[q] & 0xFFFFu, hi = wds[q] >> 16;
      if (((lo >> 7) & 0xFFu) == 0xFFu || ((hi >> 7) & 0xFFu) == 0xFFu) loc = 1;
    }
  }
  if (loc) atomicOr(&found, 1);
  __syncthreads();
  if (threadIdx.x == 0) flags[b] = found;
}

// ---- prep: elementwise convert to bf16 -------------------------------------
__global__ __launch_bounds__(256) void cvt_bf16(const void* __restrict__ src,
                                                unsigned short* __restrict__ dst,
                                                int n4, const int* __restrict__ flags, int idx) {
  const bool f32 = flags[idx] != 0;
  int i = blockIdx.x * 256 + threadIdx.x;
  if (i < n4) {
    float4 v = ld4_rt(src, (size_t)i * 4, f32);
    ushort4 o;
    o.x = f2bf(v.x); o.y = f2bf(v.y); o.z = f2bf(v.z); o.w = f2bf(v.w);
    *(ushort4*)&dst[(size_t)i * 4] = o;
  }
}

// ---- prep: all 4 weight transposes in one launch ---------------------------
__global__ __launch_bounds__(256) void transpose_all(
    const void* __restrict__ Wq, const void* __restrict__ Wk,
    const void* __restrict__ Wv, const void* __restrict__ Wo,
    unsigned short* __restrict__ WqkvT, unsigned short* __restrict__ WoT,
    const int* __restrict__ flags) {
  const int z = blockIdx.z;
  const void* srcs[4] = {Wq, Wk, Wv, Wo};
  unsigned short* dsts[4] = {WqkvT, WqkvT + (size_t)KO * 2048, WqkvT + (size_t)VO * 2048, WoT};
  const int Ns[4] = {2048, 512, 512, 2048};
  const int N = Ns[z];
  if (blockIdx.x * 64 >= N) return;
  const void* src = srcs[z];
  unsigned short* dst = dsts[z];
  const bool f32 = flags[3 + z] != 0;
  const int K = 2048;
  __shared__ unsigned short tile[64][65];
  const int t = threadIdx.x;
  const int n0 = blockIdx.x * 64, k0 = blockIdx.y * 64;
  const int cr = t >> 4, cc = (t & 15) * 4;
#pragma unroll
  for (int rr = 0; rr < 4; ++rr) {
    int row = rr * 16 + cr;
    float4 v = ld4_rt(src, (size_t)(k0 + row) * N + n0 + cc, f32);
    tile[row][cc + 0] = f2bf(v.x);
    tile[row][cc + 1] = f2bf(v.y);
    tile[row][cc + 2] = f2bf(v.z);
    tile[row][cc + 3] = f2bf(v.w);
  }
  __syncthreads();
#pragma unroll
  for (int rr = 0; rr < 4; ++rr) {
    int nrow = rr * 16 + cr;
    ushort4 o;
    o.x = tile[cc + 0][nrow];
    o.y = tile[cc + 1][nrow];
    o.z = tile[cc + 2][nrow];
    o.w = tile[cc + 3][nrow];
    *(ushort4*)&dst[(size_t)(n0 + nrow) * K + k0 + cc] = o;
  }
}

// ---------------------------------------------------------------------------
// 256x256 8-phase MFMA GEMM (m201-style, plain HIP). 512 thr = 8 waves (2Mx4N),
// BK=64, per-wave output 128x64 (acc[8][4] f32x4). LDS 128 KB: 2 buf x
// {A,B} x 2 halves x [128][64] bf16, chunk-XOR swizzled (slot = chunk^(row&7),
// pre-swizzled global source; every ds_read_b128 lands 2 lanes/16B slot).
// Phase p: {ds_read subtile || stage 1 half-tile} ; s_barrier ; 16 MFMA in
// setprio(1) ; s_barrier. Quadrants per K-tile: (0,0),(0,1),(1,1),(1,0) --
// B halves free after P2/P6, A halves after P3/P7. Stage slots:
//   P1: A0(buf1, tile 2i+1)   P5: A0(buf0, tile 2i+2)
//   P2: A1(buf1, tile 2i+1)   P6: A1(buf0, tile 2i+2)
//   P3: B0(buf0, tile 2i+2)   P7: B0(buf1, tile 2i+3)
//   P4: B1(buf0, tile 2i+2)   P8: B1(buf1, tile 2i+3)
// vmcnt(4) ONLY at P4/P8 (T4): leaves the 2 newest half-tiles in flight,
// forces exactly the halves consumed 1 phase later. Tail iter drains to 0.
// FUSE=1: RoPE+RMSNorm epilogue on q/k heads (wave owns one 64-col head),
// V heads written transposed to vt.
// ---------------------------------------------------------------------------
template <typename CT, int FUSE>
__global__ __launch_bounds__(512, 2) void gemm256(const unsigned short* __restrict__ A,
                                                  const unsigned short* __restrict__ Bt,
                                                  CT* __restrict__ C,
                                                  int M, int N, int K, int lda,
                                                  const void* __restrict__ cosp,
                                                  const void* __restrict__ sinp,
                                                  const int* __restrict__ flags,
                                                  unsigned short* __restrict__ vt) {
  __shared__ __align__(16) unsigned short LA[2][2][128 * 64];  // [buf][half][row][slot]
  __shared__ __align__(16) unsigned short LB[2][2][128 * 64];
  const int t = threadIdx.x;             // 0..511
  const int lane = t & 63, w = t >> 6;   // 8 waves
  const int wm = w >> 2;                 // A half (0..1): rows wm*128..+127
  const int wn = w & 3;                  // col block (0..3): cols wn*64..+63
  const int g = lane >> 4, m16 = lane & 15;
  const int sw = m16 & 7;                // read-side chunk XOR
  // XCD swizzle (nwg % 8 == 0 for our grids)
  const int nwg = gridDim.x * gridDim.y;
  const int orig = blockIdx.y * gridDim.x + blockIdx.x;
  const int swz = (orig & 7) * (nwg >> 3) + (orig >> 3);
  const int m0 = (swz / gridDim.x) * 256, n0 = (swz % gridDim.x) * 256;
  // staging: thread t covers rows {t>>3, 64+(t>>3)} of a [128][64] half-tile,
  // source chunk pre-swizzled so linear LDS dest holds slot = chunk^(row&7)
  const int grow = t >> 3;
  const int gch = (t & 7) ^ (grow & 7);
  const unsigned short* gA0 = A + (size_t)(m0 + grow) * lda + gch * 8;
  const unsigned short* gA1 = A + (size_t)(m0 + 128 + grow) * lda + gch * 8;
  const unsigned short* gB0 = Bt + (size_t)(n0 + grow) * K + gch * 8;
  const unsigned short* gB1 = Bt + (size_t)(n0 + 128 + grow) * K + gch * 8;

  f32x4 acc[8][4] = {};
  bf16x8 a[4][2], b[4][2];

#define STG(gp, stride, lp)                              \
  do {                                                   \
    glds16((gp), (lp) + t * 8);                          \
    glds16((gp) + (size_t)64 * (stride), (lp) + 4096 + t * 8); \
  } while (0)
#define LDA_(buf_, mh_)                                                          \
  do {                                                                           \
    const unsigned short* ab_ = &LA[buf_][wm][0];                                \
    _Pragma("unroll") for (int i_ = 0; i_ < 4; ++i_) {                           \
      const int row_ = ((mh_)*4 + i_) * 16 + m16;                                \
      a[i_][0] = *(const bf16x8*)&ab_[row_ * 64 + ((g ^ sw) * 8)];               \
      a[i_][1] = *(const bf16x8*)&ab_[row_ * 64 + (((4 + g) ^ sw) * 8)];         \
    }                                                                            \
  } while (0)
#define LDB_(buf_, j_)                                                           \
  do {                                                                           \
    const unsigned short* bb_ = &LB[buf_][wn >> 1][0];                           \
    const int row_ = (wn & 1) * 64 + (j_)*16 + m16;                              \
    b[j_][0] = *(const bf16x8*)&bb_[row_ * 64 + ((g ^ sw) * 8)];                 \
    b[j_][1] = *(const bf16x8*)&bb_[row_ * 64 + (((4 + g) ^ sw) * 8)];           \
  } while (0)
#define MFQ(mh_, nh_)                                                            \
  do {                                                                           \
    __builtin_amdgcn_s_setprio(1);                                               \
    _Pragma("unroll") for (int i_ = 0; i_ < 4; ++i_)                             \
      _Pragma("unroll") for (int jj_ = 0; jj_ < 2; ++jj_)                        \
        _Pragma("unroll") for (int kk_ = 0; kk_ < 2; ++kk_)                      \
          acc[(mh_)*4 + i_][(nh_)*2 + jj_] =                                     \
              __builtin_amdgcn_mfma_f32_16x16x32_bf16(                           \
                  a[i_][kk_], b[(nh_)*2 + jj_][kk_],                             \
                  acc[(mh_)*4 + i_][(nh_)*2 + jj_], 0, 0, 0);                    \
    __builtin_amdgcn_s_setprio(0);                                               \
  } while (0)
#define SBAR()                              \
  do {                                      \
    __builtin_amdgcn_sched_barrier(0);      \
    __builtin_amdgcn_s_barrier();           \
    __builtin_amdgcn_sched_barrier(0);      \
  } while (0)

  // prologue: tile0 -> buf0 (A0,A1,B0,B1); tile1 B -> buf1. 12 loads; wait 8.
  STG(gA0, lda, &LA[0][0][0]);
  STG(gA1, lda, &LA[0][1][0]);
  STG(gB0, K, &LB[0][0][0]);
  STG(gB1, K, &LB[0][1][0]);
  STG(gB0 + 64, K, &LB[1][0][0]);
  STG(gB1 + 64, K, &LB[1][1][0]);
  asm volatile("s_waitcnt vmcnt(4)" ::: "memory");
  SBAR();

  const int NIT = K >> 7;  // 2 K-tiles per iteration
  int kb = 64;             // k0 of tile 2i+1 (A staged into buf1 at P1/P2)
  for (int it = 0; it < NIT; ++it) {
    const bool more = (it + 1 < NIT);
    const int kn = kb + 64;    // tile 2i+2
    const int knb = kb + 128;  // tile 2i+3
    // ---- K-tile 2i (buf0) ----
    // P1
    LDA_(0, 0); LDB_(0, 0); LDB_(0, 1);
    STG(gA0 + kb, lda, &LA[1][0][0]);
    SBAR(); MFQ(0, 0); SBAR();
    // P2
    LDB_(0, 2); LDB_(0, 3);
    STG(gA1 + kb, lda, &LA[1][1][0]);
    SBAR(); MFQ(0, 1); SBAR();
    // P3
    LDA_(0, 1);
    if (more) STG(gB0 + kn, K, &LB[0][0][0]);
    SBAR(); MFQ(1, 1); SBAR();
    // P4
    if (more) {
      STG(gB1 + kn, K, &LB[0][1][0]);
      asm volatile("s_waitcnt vmcnt(4)" ::: "memory");
    } else {
      asm volatile("s_waitcnt vmcnt(0)" ::: "memory");
    }
    SBAR(); MFQ(1, 0); SBAR();
    // ---- K-tile 2i+1 (buf1) ----
    // P5
    LDA_(1, 0); LDB_(1, 0); LDB_(1, 1);
    if (more) STG(gA0 + kn, lda, &LA[0][0][0]);
    SBAR(); MFQ(0, 0); SBAR();
    // P6
    LDB_(1, 2); LDB_(1, 3);
    if (more) STG(gA1 + kn, lda, &LA[0][1][0]);
    SBAR(); MFQ(0, 1); SBAR();
    // P7
    LDA_(1, 1);
    if (more) STG(gB0 + knb, K, &LB[1][0][0]);
    SBAR(); MFQ(1, 1); SBAR();
    // P8
    if (more) {
      STG(gB1 + knb, K, &LB[1][1][0]);
      asm volatile("s_waitcnt vmcnt(4)" ::: "memory");
    } else {
      asm volatile("s_waitcnt vmcnt(0)" ::: "memory");
    }
    SBAR(); MFQ(1, 0); SBAR();
    kb += 128;
  }
#undef STG
#undef LDA_
#undef LDB_
#undef MFQ
#undef SBAR

  const int rbase = m0 + wm * 128;
  if constexpr (FUSE) {
    const int colbase = n0 + wn * 64;     // 64-aligned -> exactly one head/wave
    if (colbase < VO) {                   // q or k head: RoPE + RMSNorm
      const bool cf = flags[1] != 0, sf = flags[2] != 0;
      const float post = (colbase < KO) ? QSCALE : 1.0f;  // q: fold softmax scale
#pragma unroll
      for (int i = 0; i < 8; ++i)
#pragma unroll
        for (int r = 0; r < 4; ++r) {
          const int row = rbase + i * 16 + g * 4 + r;
          const int l = row & (LL - 1);
          const float c0 = ld1_rt(cosp, l * 32 + m16, cf);
          const float c1 = ld1_rt(cosp, l * 32 + 16 + m16, cf);
          const float s0 = ld1_rt(sinp, l * 32 + m16, sf);
          const float s1 = ld1_rt(sinp, l * 32 + 16 + m16, sf);
          const float x0 = acc[i][0][r], x1 = acc[i][1][r];
          const float x2 = acc[i][2][r], x3 = acc[i][3][r];
          const float r0 = x0 * c0 - x2 * s0;
          const float r1 = x1 * c1 - x3 * s1;
          const float r2 = x2 * c0 + x0 * s0;
          const float r3 = x3 * c1 + x1 * s1;
          float ss = r0 * r0 + r1 * r1 + r2 * r2 + r3 * r3;
#pragma unroll
          for (int off = 1; off < 16; off <<= 1) ss += __shfl_xor(ss, off);
          const float sc = rsqrtf(ss * (1.0f / HD) + EPS) * post;
          CT* cr = &C[(size_t)row * N + colbase + m16];
          store1(cr + 0, r0 * sc);
          store1(cr + 16, r1 * sc);
          store1(cr + 32, r2 * sc);
          store1(cr + 48, r3 * sc);
        }
    } else {
      // V head: write transposed into vt[b][kvh][d=64][L]
      const int bb = rbase >> 11;
      const int lb = rbase & (LL - 1);
      const int kvh = (colbase - VO) >> 6;
      unsigned short* vb = vt + (size_t)(bb * NKV + kvh) * 64 * LL;
#pragma unroll
      for (int j = 0; j < 4; ++j)
#pragma unroll
        for (int i = 0; i < 8; ++i) {
          ushort4 pw;
          pw.x = f2bf(acc[i][j][0]); pw.y = f2bf(acc[i][j][1]);
          pw.z = f2bf(acc[i][j][2]); pw.w = f2bf(acc[i][j][3]);
          *(ushort4*)&vb[(size_t)(j * 16 + m16) * LL + lb + i * 16 + g * 4] = pw;
        }
    }
    return;
  }
#pragma unroll
  for (int i = 0; i < 8; ++i)
#pragma unroll
    for (int j = 0; j < 4; ++j)
#pragma unroll
      for (int r = 0; r < 4; ++r) {
        int row = rbase + i * 16 + g * 4 + r;
        int col = n0 + wn * 64 + j * 16 + m16;
        store1(&C[(size_t)row * N + col], acc[i][j][r]);
      }
}

// ---------------------------------------------------------------------------
// MFMA causal GQA flash attention with STATIC-MAX softmax (unchanged from R5).
// ---------------------------------------------------------------------------
__global__ __launch_bounds__(256) void attn_mfma(unsigned short* __restrict__ qkv,
                                                 const unsigned short* __restrict__ vt) {
  __shared__ __align__(16) unsigned short Ks[2][64 * 64];  // [key][d], chunk-swizzled
  __shared__ __align__(16) unsigned short Vs[2][64 * 64];  // [d][key], chunk-swizzled
  __shared__ __align__(16) unsigned short Pt[4][64 * 16];  // per-wave P^T [key][qrow]
  const int t = threadIdx.x, lane = t & 63, w = t >> 6;
  const int g = lane >> 4, m16 = lane & 15;
  const int h = blockIdx.x, b = blockIdx.y;
  const int qt = (LL / 64 - 1) - blockIdx.z;  // longest blocks dispatch first
  const int kvh = h >> 2;
  const int q0 = qt * 64, qr0 = q0 + w * 16;

  bf16x8 qf0, qf1;
  {
    const unsigned short* qrow = &qkv[(size_t)(b * LL + qr0 + m16) * QS + h * 64 + g * 8];
    qf0 = *(const bf16x8*)&qrow[0];
    qf1 = *(const bf16x8*)&qrow[32];
  }
  f32x4 Oacc[4] = {};
  float lrow[4] = {0.f, 0.f, 0.f, 0.f};

  const int lr = lane >> 3;            // row within the 8-row group
  const int lc = (lane & 7) ^ lr;      // swizzled source 16B chunk
  const unsigned short* gK = &qkv[(size_t)(b * LL) * QS + KO + kvh * 64 + lc * 8];
  const unsigned short* gV = &vt[((size_t)(b * NKV + kvh) * 64 + w * 16 + lr) * LL + lc * 8];
  const int dbase = w * 1024 + lane * 8;  // LDS dest (shorts): wave-linear
  const int nIter = q0 / 64 + 1;

  // prologue: stage tile 0 into buffer 0
#pragma unroll
  for (int c = 0; c < 2; ++c) {
    glds16(gK + (size_t)(w * 16 + c * 8 + lr) * QS, &Ks[0][dbase + c * 512]);
    glds16(gV + (size_t)c * 8 * LL, &Vs[0][dbase + c * 512]);
  }
  __syncthreads();  // vmcnt(0) drain included

  const int sw8 = (m16 & 7) * 8;  // read-side chunk swizzle (shorts)
  for (int it = 0; it < nIter; ++it) {
    const int j0 = it * 64;
    const int cur = it & 1;
    if (it + 1 < nIter) {  // prefetch next tile into the other buffer
      const int nj = j0 + 64;
#pragma unroll
      for (int c = 0; c < 2; ++c) {
        glds16(gK + (size_t)(nj + w * 16 + c * 8 + lr) * QS, &Ks[cur ^ 1][dbase + c * 512]);
        glds16(gV + (size_t)c * 8 * LL + nj, &Vs[cur ^ 1][dbase + c * 512]);
      }
    }
    const unsigned short* KsB = Ks[cur];
    const unsigned short* VsB = Vs[cur];

    // S = Q K^T
    f32x4 S[4];
#pragma unroll
    for (int jt = 0; jt < 4; ++jt) {
      const int rb = (jt * 16 + m16) * 64;
      bf16x8 kf0 = *(const bf16x8*)&KsB[rb + ((g * 8) ^ sw8)];
      bf16x8 kf1 = *(const bf16x8*)&KsB[rb + (((g + 4) * 8) ^ sw8)];
      f32x4 z = {0.f, 0.f, 0.f, 0.f};
      z = __builtin_amdgcn_mfma_f32_16x16x32_bf16(qf0, kf0, z, 0, 0, 0);
      S[jt] = __builtin_amdgcn_mfma_f32_16x16x32_bf16(qf1, kf1, z, 0, 0, 0);
    }
    // static-max softmax: p = 2^(S - SM_BIAS); mask only on the diagonal tile
    if (j0 == q0) {
#pragma unroll
      for (int jt = 0; jt < 4; ++jt)
#pragma unroll
        for (int r = 0; r < 4; ++r) {
          int col = q0 + jt * 16 + m16;
          int row = qr0 + g * 4 + r;
          float p = __builtin_amdgcn_exp2f(S[jt][r] - SM_BIAS);
          p = (col <= row) ? p : 0.f;
          S[jt][r] = p;
          lrow[r] += p;
        }
    } else {
#pragma unroll
      for (int jt = 0; jt < 4; ++jt)
#pragma unroll
        for (int r = 0; r < 4; ++r) {
          float p = __builtin_amdgcn_exp2f(S[jt][r] - SM_BIAS);
          S[jt][r] = p;
          lrow[r] += p;
        }
    }
    // P -> per-wave Pt (transposed [key][qrow]): 4 vector b64 writes
#pragma unroll
    for (int jt = 0; jt < 4; ++jt) {
      ushort4 pw;
      pw.x = f2bf(S[jt][0]); pw.y = f2bf(S[jt][1]);
      pw.z = f2bf(S[jt][2]); pw.w = f2bf(S[jt][3]);
      *(ushort4*)&Pt[w][(jt * 16 + m16) * 16 + g * 4] = pw;
    }
    // A-fragment reload via hardware transpose read (lane stride 8 B in-group)
    s16x4 a0, a1, b0, b1;
    {
      __attribute__((address_space(3))) unsigned short* p3 =
          (__attribute__((address_space(3))) unsigned short*)&Pt[w][g * 128 + m16 * 4];
      unsigned paddr = (unsigned)(size_t)p3;
      asm volatile(
          "s_waitcnt lgkmcnt(0)\n\t"
          "ds_read_b64_tr_b16 %0, %4\n\t"
          "ds_read_b64_tr_b16 %1, %4 offset:128\n\t"
          "ds_read_b64_tr_b16 %2, %4 offset:1024\n\t"
          "ds_read_b64_tr_b16 %3, %4 offset:1152\n\t"
          "s_waitcnt lgkmcnt(0)"
          : "=&v"(a0), "=&v"(a1), "=&v"(b0), "=&v"(b1)
          : "v"(paddr)
          : "memory");
      __builtin_amdgcn_sched_barrier(0);  // rule #18: keep MFMAs below the wait
    }
    bf16x8 pf0 = __builtin_shufflevector(a0, a1, 0, 1, 2, 3, 4, 5, 6, 7);
    bf16x8 pf1 = __builtin_shufflevector(b0, b1, 0, 1, 2, 3, 4, 5, 6, 7);
    // O += P V
#pragma unroll
    for (int dt = 0; dt < 4; ++dt) {
      const int rb = (dt * 16 + m16) * 64;
      bf16x8 vf0 = *(const bf16x8*)&VsB[rb + ((g * 8) ^ sw8)];
      bf16x8 vf1 = *(const bf16x8*)&VsB[rb + (((g + 4) * 8) ^ sw8)];
      Oacc[dt] = __builtin_amdgcn_mfma_f32_16x16x32_bf16(pf0, vf0, Oacc[dt], 0, 0, 0);
      Oacc[dt] = __builtin_amdgcn_mfma_f32_16x16x32_bf16(pf1, vf1, Oacc[dt], 0, 0, 0);
    }
    // single barrier per tile: syncs waves AND drains prefetch vmcnt
    __syncthreads();
  }
  // epilogue: reduce l across the 16-lane column groups, normalize, store
  float inv[4];
#pragma unroll
  for (int r = 0; r < 4; ++r) {
#pragma unroll
    for (int off = 1; off < 16; off <<= 1) lrow[r] += __shfl_xor(lrow[r], off);
    inv[r] = 1.0f / lrow[r];
  }
#pragma unroll
  for (int dt = 0; dt < 4; ++dt)
#pragma unroll
    for (int r = 0; r < 4; ++r) {
      int row = qr0 + g * 4 + r;
      qkv[(size_t)(b * LL + row) * QS + h * 64 + dt * 16 + m16] = f2bf(Oacc[dt][r] * inv[r]);
    }
}

// ---------------------------------------------------------------------------
extern "C" void kernel_launch(void* const* d_in, const int* in_sizes, int n_in,
                              void* d_out, int out_size, void* d_ws, size_t ws_size,
                              hipStream_t stream) {
  const void* x = d_in[0];
  const void* cosp = d_in[1];
  const void* sinp = d_in[2];
  const void* Wq = d_in[3];
  const void* Wk = d_in[4];
  const void* Wv = d_in[5];
  const void* Wo = d_in[6];
  float* out = (float*)d_out;

  // ws (bf16): xb [4096][2048] | qkvb [4096][3072] | WqkvT [3072][2048]
  //          | WoT [2048][2048] | Vt [2*8][64][2048]
  char* w0 = (char*)d_ws;
  int* flags = (int*)w0;
  unsigned short* xb = (unsigned short*)(w0 + 256);
  unsigned short* qkvb = xb + (size_t)MM * 2048;
  unsigned short* WqkvT = qkvb + (size_t)MM * QS;
  unsigned short* WoT = WqkvT + (size_t)QS * 2048;
  unsigned short* vt = WoT + (size_t)2048 * 2048;

  detect_all<<<7, 256, 0, stream>>>(
      (const unsigned short*)x, (const unsigned short*)cosp, (const unsigned short*)sinp,
      (const unsigned short*)Wq, (const unsigned short*)Wk, (const unsigned short*)Wv,
      (const unsigned short*)Wo, flags);
  cvt_bf16<<<MM * 2048 / 4 / 256, 256, 0, stream>>>(x, xb, MM * 2048 / 4, flags, 0);
  transpose_all<<<dim3(32, 32, 4), 256, 0, stream>>>(Wq, Wk, Wv, Wo, WqkvT, WoT, flags);
  // fused QKV projection + RoPE/RMSNorm epilogue (q pre-scaled) + V^T to vt
  gemm256<unsigned short, 1><<<dim3(QS / 256, MM / 256), 512, 0, stream>>>(
      xb, WqkvT, qkvb, MM, QS, 2048, 2048, cosp, sinp, flags, vt);
  // causal GQA attention, O in-place into q columns; longest qt first
  attn_mfma<<<dim3(NH, BB, LL / 64), 256, 0, stream>>>(qkvb, vt);
  // output projection: qkv's q columns (lda=3072) @ WoT -> f32 out
  gemm256<float, 0><<<dim3(2048 / 256, MM / 256), 512, 0, stream>>>(
      qkvb, WoT, out, MM, 2048, 2048, QS, nullptr, nullptr, nullptr, nullptr);
}